// Round 9
// baseline (110.497 us; speedup 1.0000x reference)
//
#include <hip/hip_runtime.h>
#include <climits>

#define A_N 33600
#define G_N 256
#define NC 80
#define KK 10
#define CAP 2048                 // max candidates per gt (layout worst case ~1408)
#define GCHUNK 32
#define NCHUNK (G_N / GCHUNK)    // 8
#define AB_N 132                 // ceil(A_N/256)
#define PAIR_BLKS (AB_N * NCHUNK)          // 1056
#define FILL_N ((A_N * 81) / 4)            // 680400 float4 for out_scores
#define FILL_BLKS ((FILL_N + 255) / 256)   // 2658
#define NLD 32                   // CAP / 64

// Monotone float->uint mapping: preserves total order (incl. +/-inf).
__device__ __forceinline__ unsigned int ford(float f) {
    unsigned int u = __float_as_uint(f);
    return (u & 0x80000000u) ? ~u : (u | 0x80000000u);
}

__device__ __forceinline__ unsigned long long umin64(unsigned long long a, unsigned long long b) {
    return a < b ? a : b;
}

// Two roles in one dispatch (independent buffers -> no cross-role races):
//  bid < PAIR_BLKS: anchor-parallel sparse emission, gt-chunked (round-8 body)
//    with logsum computed inline per-thread (redundant across the 8 gt-chunks;
//    same ascending class order -> identical value in every duplicate).
//  bid >= PAIR_BLKS: negative-default output fills + assigned=-1.
// cnt must be zeroed by the preceding memset dispatch.
__global__ __launch_bounds__(256) void k_main(
    const float* __restrict__ scores, const float* __restrict__ pred_b,
    const float* __restrict__ anchors, const int* __restrict__ gt_labels,
    const float* __restrict__ gt_b,
    unsigned long long* __restrict__ bucket, int* __restrict__ cnt,
    int* __restrict__ assigned,
    float* __restrict__ out_labels, float4* __restrict__ out_bbox4,
    float4* __restrict__ out_scores4)
{
    int bid = blockIdx.x, tid = threadIdx.x;

    if (bid >= PAIR_BLKS) {        // ---- fill role ----
        int t = (bid - PAIR_BLKS) * 256 + tid;
        float4 z4 = make_float4(0.f, 0.f, 0.f, 0.f);
        if (t < A_N) { assigned[t] = -1; out_labels[t] = (float)NC; out_bbox4[t] = z4; }
        if (t < FILL_N) out_scores4[t] = z4;
        return;
    }

    // ---- pair role ----
    __shared__ float4 gbox[GCHUNK];
    __shared__ int glab[GCHUNK];
    int gc = bid & (NCHUNK - 1);
    int ab = bid >> 3;
    if (tid < GCHUNK) {
        gbox[tid] = ((const float4*)gt_b)[gc * GCHUNK + tid];
        glab[tid] = gt_labels[gc * GCHUNK + tid];
    }
    __syncthreads();

    int a = ab * 256 + tid;
    if (a >= A_N) return;

    float4 pb = ((const float4*)pred_b)[a];
    float2 ap = ((const float2*)anchors)[a];
    float area_p = (pb.z - pb.x) * (pb.w - pb.y);

    // logsum[a] = -sum_c (max(s,0) + log1p(exp(-|s|)))  (ascending c, fp32)
    const float4* row = (const float4*)(scores + (long)a * NC);
    float ls = 0.f;
    #pragma unroll 4
    for (int i = 0; i < NC / 4; i++) {
        float4 v = row[i];
        ls -= fmaxf(v.x, 0.f) + log1pf(expf(-fabsf(v.x)));
        ls -= fmaxf(v.y, 0.f) + log1pf(expf(-fabsf(v.y)));
        ls -= fmaxf(v.z, 0.f) + log1pf(expf(-fabsf(v.z)));
        ls -= fmaxf(v.w, 0.f) + log1pf(expf(-fabsf(v.w)));
    }

    #pragma unroll 4
    for (int g = 0; g < GCHUNK; g++) {
        float4 gb = gbox[g];               // LDS broadcast
        // inside == in_gt exactly (RADIUS=2.5 makes the center test redundant)
        bool in_gt = (ap.x >= gb.x) & (ap.x <= gb.z) & (ap.y >= gb.y) & (ap.y <= gb.w);
        if (!in_gt) continue;

        float ltx = fmaxf(gb.x, pb.x), lty = fmaxf(gb.y, pb.y);
        float rbx = fminf(gb.z, pb.z), rby = fminf(gb.w, pb.w);
        float w = fmaxf(rbx - ltx, 0.f), h = fmaxf(rby - lty, 0.f);
        float overlap = w * h;
        if (!(overlap > 0.f)) continue;    // inside & iou==0 -> +inf, never selected

        int gg = gc * GCHUNK + g;
        float area_g = (gb.z - gb.x) * (gb.w - gb.y);
        float uni = area_g + area_p - overlap + 1e-6f;
        float iou = overlap / uni;
        float s = scores[(long)a * NC + glab[g]];
        // log_sigmoid(s)-log_sigmoid(-s) == s (shared log1p term cancels)
        float cost = (-s - ls) + 3.0f * (-logf(iou));
        unsigned long long key = ((unsigned long long)ford(cost) << 32) | (unsigned)a;

        int slot = atomicAdd(&cnt[gg], 1);
        if ((unsigned)slot < CAP) bucket[(size_t)gg * CAP + slot] = key;
    }
}

// One WAVE per gt (grid G_N x 64): select min(cnt,10) smallest keys (exact,
// order-independent over unique keys), scatter atomicMax, record poslist.
// cnt==0: lazy early-break ascending scan for the lowest-index anchor with
// overlap>0 (all iou>0 anchors tie at cost exactly 1e10 -> index tiebreak;
// iou==0 is +inf). Expected 1-2 batches (P(hit/batch) ~ 95%).
__global__ __launch_bounds__(64) void k_select(
    const unsigned long long* __restrict__ bucket, const int* __restrict__ cnt_arr,
    const float* __restrict__ pred_b, const float* __restrict__ gt_b,
    int* __restrict__ assigned, int* __restrict__ poslist)
{
    int g = blockIdx.x, lane = threadIdx.x;
    int cnt = cnt_arr[g];

    if (cnt == 0) {
        float4 gb = ((const float4*)gt_b)[g];
        int found = INT_MAX;
        for (int base = 0; base < A_N; base += 64) {     // A_N = 525*64 exact
            int a = base + lane;
            float4 pb = ((const float4*)pred_b)[a];
            float w = fminf(gb.z, pb.z) - fmaxf(gb.x, pb.x);
            float h = fminf(gb.w, pb.w) - fmaxf(gb.y, pb.y);
            bool hit = (w > 0.f) && (h > 0.f);
            if (__ballot(hit)) { if (hit) found = a; break; }  // first hit batch holds the min
        }
        #pragma unroll
        for (int off = 32; off; off >>= 1) found = min(found, __shfl_xor(found, off));
        int m = (found == INT_MAX) ? 0 : found;
        if (lane == 0) atomicMax(&assigned[m], g);
        if (lane < KK) poslist[g * KK + lane] = (lane == 0) ? m : -1;
        return;
    }

    int k = cnt < KK ? cnt : KK;
    int nreal = cnt < CAP ? cnt : CAP;
    const unsigned long long* bk = bucket + (size_t)g * CAP;

    unsigned long long kv[NLD];
    #pragma unroll
    for (int i = 0; i < NLD; i++) {
        kv[i] = ~0ull;
        if (i * 64 < nreal) {                    // wave-uniform guard
            int idx = lane + i * 64;
            if (idx < nreal) kv[i] = bk[idx];
        }
    }

    int mywin = -1;
    for (int it = 0; it < k; it++) {
        unsigned long long m = ~0ull;
        #pragma unroll
        for (int i = 0; i < NLD; i++) if (i * 64 < nreal) m = umin64(m, kv[i]);
        #pragma unroll
        for (int off = 32; off; off >>= 1) m = umin64(m, __shfl_xor(m, off));
        if (lane == it) mywin = (int)(m & 0xffffffffu);
        #pragma unroll
        for (int i = 0; i < NLD; i++) if (i * 64 < nreal) { if (kv[i] == m) kv[i] = ~0ull; }
    }

    if (lane < KK) poslist[g * KK + lane] = (lane < k) ? mywin : -1;
    if (lane < k) atomicMax(&assigned[mywin], g);
}

// Positives-only output fix-up: <=2560 candidate anchors; assigned[] is final
// (stream order). Duplicate entries write identical values -> deterministic.
__global__ __launch_bounds__(256) void k_fix(
    const int* __restrict__ poslist, const int* __restrict__ assigned,
    const int* __restrict__ gt_labels, const float* __restrict__ gt_b,
    const float* __restrict__ pred_b,
    float* __restrict__ out_labels, float4* __restrict__ out_bbox4,
    float* __restrict__ out_scores)
{
    int t = blockIdx.x * 256 + threadIdx.x;
    if (t >= G_N * KK) return;
    int a = poslist[t];
    if (a < 0) return;
    int g = assigned[a];               // final; >= 0 since a was scattered by someone
    int label = gt_labels[g];
    float4 gb = ((const float4*)gt_b)[g];
    float4 pb = ((const float4*)pred_b)[a];
    float w = fminf(gb.z, pb.z) - fmaxf(gb.x, pb.x);
    float h = fminf(gb.w, pb.w) - fmaxf(gb.y, pb.y);
    float ovl = fmaxf(w, 0.f) * fmaxf(h, 0.f);
    float area_g = (gb.z - gb.x) * (gb.w - gb.y);
    float area_p = (pb.z - pb.x) * (pb.w - pb.y);
    float uni = area_g + area_p - ovl + 1e-6f;
    float iou = ovl / uni;
    out_labels[a] = (float)label;
    out_bbox4[a] = gb;
    out_scores[(long)a * (NC + 1) + label] = iou;
}

extern "C" void kernel_launch(void* const* d_in, const int* in_sizes, int n_in,
                              void* d_out, int out_size, void* d_ws, size_t ws_size,
                              hipStream_t stream) {
    const float* pred_scores   = (const float*)d_in[0];
    const float* pred_bboxes   = (const float*)d_in[1];
    const float* anchor_points = (const float*)d_in[2];
    const int*   gt_labels     = (const int*)d_in[3];
    const float* gt_bboxes     = (const float*)d_in[4];

    char* ws = (char*)d_ws;
    unsigned long long* bucket = (unsigned long long*)ws;         // G*CAP u64 (8B-aligned first)
    size_t off = (size_t)G_N * CAP * 8;                           // 4 MiB
    int* assigned = (int*)(ws + off);   off += (size_t)A_N * 4;
    int* cnt      = (int*)(ws + off);   off += (size_t)G_N * 4;
    int* poslist  = (int*)(ws + off);

    float*  out_labels = (float*)d_out;                 // A
    float4* out_bbox4  = (float4*)(out_labels + A_N);   // A float4 (16B-aligned)
    float*  out_scores = out_labels + 5 * (size_t)A_N;  // A*81 (16B-aligned)

    hipMemsetAsync(cnt, 0, (size_t)G_N * sizeof(int), stream);
    k_main<<<PAIR_BLKS + FILL_BLKS, 256, 0, stream>>>(
        pred_scores, pred_bboxes, anchor_points, gt_labels, gt_bboxes,
        bucket, cnt, assigned, out_labels, out_bbox4, (float4*)out_scores);
    k_select<<<G_N, 64, 0, stream>>>(bucket, cnt, pred_bboxes, gt_bboxes,
                                     assigned, poslist);
    k_fix<<<(G_N * KK + 255) / 256, 256, 0, stream>>>(poslist, assigned, gt_labels,
                                                      gt_bboxes, pred_bboxes,
                                                      out_labels, out_bbox4, out_scores);
}

// Round 10
// 45.792 us; speedup vs baseline: 2.4130x; 2.4130x over previous
//
#include <hip/hip_runtime.h>
#include <climits>

#define A_N 33600
#define G_N 256
#define NC 80
#define KK 10
#define CAP 2048                 // max candidates per gt (layout worst case ~1408)
#define GCHUNK 32
#define NCHUNK (G_N / GCHUNK)    // 8
#define NLD 32                   // CAP / 64
#define FILL_N ((A_N * 81) / 4)  // 680400 float4 of out_scores

// Monotone float->uint mapping: preserves total order (incl. +/-inf).
__device__ __forceinline__ unsigned int ford(float f) {
    unsigned int u = __float_as_uint(f);
    return (u & 0x80000000u) ? ~u : (u | 0x80000000u);
}

__device__ __forceinline__ unsigned long long umin64(unsigned long long a, unsigned long long b) {
    return a < b ? a : b;
}

// Init: logsum ONCE per anchor (one wave each; round-8 validated) + cnt=0 +
// assigned=-1 + negative-default outputs. 8400 blocks x 256 (2.15M threads
// covers FILL_N=680400).
__global__ __launch_bounds__(256) void k_init(
    const float* __restrict__ scores, float* __restrict__ logsum,
    int* __restrict__ cnt, int* __restrict__ assigned,
    float* __restrict__ out_labels, float4* __restrict__ out_bbox4,
    float4* __restrict__ out_scores4)
{
    int t = blockIdx.x * 256 + threadIdx.x;
    int wv = t >> 6, lane = t & 63;
    float4 z4 = make_float4(0.f, 0.f, 0.f, 0.f);

    if (t < G_N) cnt[t] = 0;
    if (t < A_N) { assigned[t] = -1; out_labels[t] = (float)NC; out_bbox4[t] = z4; }
    if (t < FILL_N) out_scores4[t] = z4;

    // logsum[a] = sum_c log_sigmoid(-s[a,c]) = -sum_c (max(s,0)+log1p(exp(-|s|)))
    const float* row = scores + (long)wv * NC;
    float acc = 0.f;
    for (int c = lane; c < NC; c += 64) {
        float s = row[c];
        acc -= (fmaxf(s, 0.f) + log1pf(expf(-fabsf(s))));
    }
    #pragma unroll
    for (int off = 32; off > 0; off >>= 1) acc += __shfl_down(acc, off);
    if (lane == 0) logsum[wv] = acc;
}

// Anchor-parallel sparse emission, gt-chunked for occupancy (round-5 body,
// validated): grid (132, 8) x 256. Early continue; per-thread atomicAdd
// (compiler wave-aggregates uniform-address increments).
// inside == in_gt exactly (RADIUS=2.5 makes the center test redundant).
__global__ __launch_bounds__(256) void k_pairs(
    const float* __restrict__ scores, const float* __restrict__ pred_b,
    const float* __restrict__ anchors, const int* __restrict__ gt_labels,
    const float* __restrict__ gt_b, const float* __restrict__ logsum,
    unsigned long long* __restrict__ bucket, int* __restrict__ cnt)
{
    __shared__ float4 gbox[GCHUNK];
    __shared__ int glab[GCHUNK];
    int tid = threadIdx.x;
    int gc = blockIdx.y;
    if (tid < GCHUNK) {
        gbox[tid] = ((const float4*)gt_b)[gc * GCHUNK + tid];
        glab[tid] = gt_labels[gc * GCHUNK + tid];
    }
    __syncthreads();

    int a = blockIdx.x * 256 + tid;
    if (a >= A_N) return;

    float4 pb = ((const float4*)pred_b)[a];
    float2 ap = ((const float2*)anchors)[a];
    float area_p = (pb.z - pb.x) * (pb.w - pb.y);
    float ls = logsum[a];

    #pragma unroll 4
    for (int g = 0; g < GCHUNK; g++) {
        float4 gb = gbox[g];               // LDS broadcast
        bool in_gt = (ap.x >= gb.x) & (ap.x <= gb.z) & (ap.y >= gb.y) & (ap.y <= gb.w);
        if (!in_gt) continue;

        float ltx = fmaxf(gb.x, pb.x), lty = fmaxf(gb.y, pb.y);
        float rbx = fminf(gb.z, pb.z), rby = fminf(gb.w, pb.w);
        float w = fmaxf(rbx - ltx, 0.f), h = fmaxf(rby - lty, 0.f);
        float overlap = w * h;
        if (!(overlap > 0.f)) continue;    // inside & iou==0 -> +inf, never selected

        int gg = gc * GCHUNK + g;
        float area_g = (gb.z - gb.x) * (gb.w - gb.y);
        float uni = area_g + area_p - overlap + 1e-6f;
        float iou = overlap / uni;
        float s = scores[(long)a * NC + glab[g]];
        // log_sigmoid(s)-log_sigmoid(-s) == s (shared log1p term cancels)
        float cost = (-s - ls) + 3.0f * (-logf(iou));
        unsigned long long key = ((unsigned long long)ford(cost) << 32) | (unsigned)a;

        int slot = atomicAdd(&cnt[gg], 1);
        if ((unsigned)slot < CAP) bucket[(size_t)gg * CAP + slot] = key;
    }
}

// One WAVE per gt (round-9 body, validated): select min(cnt,10) smallest keys
// (exact, order-independent over unique keys), scatter atomicMax, record poslist.
// cnt==0: lazy early-break ascending scan for the lowest-index anchor with
// overlap>0 (all iou>0 anchors tie at cost exactly 1e10 -> index tiebreak;
// iou==0 is +inf).
__global__ __launch_bounds__(64) void k_select(
    const unsigned long long* __restrict__ bucket, const int* __restrict__ cnt_arr,
    const float* __restrict__ pred_b, const float* __restrict__ gt_b,
    int* __restrict__ assigned, int* __restrict__ poslist)
{
    int g = blockIdx.x, lane = threadIdx.x;
    int cnt = cnt_arr[g];

    if (cnt == 0) {
        float4 gb = ((const float4*)gt_b)[g];
        int found = INT_MAX;
        for (int base = 0; base < A_N; base += 64) {     // A_N = 525*64 exact
            int a = base + lane;
            float4 pb = ((const float4*)pred_b)[a];
            float w = fminf(gb.z, pb.z) - fmaxf(gb.x, pb.x);
            float h = fminf(gb.w, pb.w) - fmaxf(gb.y, pb.y);
            bool hit = (w > 0.f) && (h > 0.f);
            if (__ballot(hit)) { if (hit) found = a; break; }  // first hit batch holds the min
        }
        #pragma unroll
        for (int off = 32; off; off >>= 1) found = min(found, __shfl_xor(found, off));
        int m = (found == INT_MAX) ? 0 : found;
        if (lane == 0) atomicMax(&assigned[m], g);
        if (lane < KK) poslist[g * KK + lane] = (lane == 0) ? m : -1;
        return;
    }

    int k = cnt < KK ? cnt : KK;
    int nreal = cnt < CAP ? cnt : CAP;
    const unsigned long long* bk = bucket + (size_t)g * CAP;

    unsigned long long kv[NLD];
    #pragma unroll
    for (int i = 0; i < NLD; i++) {
        kv[i] = ~0ull;
        if (i * 64 < nreal) {                    // wave-uniform guard
            int idx = lane + i * 64;
            if (idx < nreal) kv[i] = bk[idx];
        }
    }

    int mywin = -1;
    for (int it = 0; it < k; it++) {
        unsigned long long m = ~0ull;
        #pragma unroll
        for (int i = 0; i < NLD; i++) if (i * 64 < nreal) m = umin64(m, kv[i]);
        #pragma unroll
        for (int off = 32; off; off >>= 1) m = umin64(m, __shfl_xor(m, off));
        if (lane == it) mywin = (int)(m & 0xffffffffu);
        #pragma unroll
        for (int i = 0; i < NLD; i++) if (i * 64 < nreal) { if (kv[i] == m) kv[i] = ~0ull; }
    }

    if (lane < KK) poslist[g * KK + lane] = (lane < k) ? mywin : -1;
    if (lane < k) atomicMax(&assigned[mywin], g);
}

// Positives-only output fix-up: <=2560 candidate anchors; assigned[] is final
// (stream order). Duplicate entries write identical values -> deterministic.
__global__ __launch_bounds__(256) void k_fix(
    const int* __restrict__ poslist, const int* __restrict__ assigned,
    const int* __restrict__ gt_labels, const float* __restrict__ gt_b,
    const float* __restrict__ pred_b,
    float* __restrict__ out_labels, float4* __restrict__ out_bbox4,
    float* __restrict__ out_scores)
{
    int t = blockIdx.x * 256 + threadIdx.x;
    if (t >= G_N * KK) return;
    int a = poslist[t];
    if (a < 0) return;
    int g = assigned[a];               // final; >= 0 since a was scattered by someone
    int label = gt_labels[g];
    float4 gb = ((const float4*)gt_b)[g];
    float4 pb = ((const float4*)pred_b)[a];
    float w = fminf(gb.z, pb.z) - fmaxf(gb.x, pb.x);
    float h = fminf(gb.w, pb.w) - fmaxf(gb.y, pb.y);
    float ovl = fmaxf(w, 0.f) * fmaxf(h, 0.f);
    float area_g = (gb.z - gb.x) * (gb.w - gb.y);
    float area_p = (pb.z - pb.x) * (pb.w - pb.y);
    float uni = area_g + area_p - ovl + 1e-6f;
    float iou = ovl / uni;
    out_labels[a] = (float)label;
    out_bbox4[a] = gb;
    out_scores[(long)a * (NC + 1) + label] = iou;
}

extern "C" void kernel_launch(void* const* d_in, const int* in_sizes, int n_in,
                              void* d_out, int out_size, void* d_ws, size_t ws_size,
                              hipStream_t stream) {
    const float* pred_scores   = (const float*)d_in[0];
    const float* pred_bboxes   = (const float*)d_in[1];
    const float* anchor_points = (const float*)d_in[2];
    const int*   gt_labels     = (const int*)d_in[3];
    const float* gt_bboxes     = (const float*)d_in[4];

    char* ws = (char*)d_ws;
    unsigned long long* bucket = (unsigned long long*)ws;         // G*CAP u64 (8B-aligned first)
    size_t off = (size_t)G_N * CAP * 8;                           // 4 MiB
    int*   assigned = (int*)(ws + off);   off += (size_t)A_N * 4;
    int*   cnt      = (int*)(ws + off);   off += (size_t)G_N * 4;
    int*   poslist  = (int*)(ws + off);   off += (size_t)G_N * KK * 4;
    float* logsum   = (float*)(ws + off);

    float*  out_labels = (float*)d_out;                 // A
    float4* out_bbox4  = (float4*)(out_labels + A_N);   // A float4 (16B-aligned)
    float*  out_scores = out_labels + 5 * (size_t)A_N;  // A*81 (16B-aligned)

    k_init<<<A_N / 4, 256, 0, stream>>>(pred_scores, logsum, cnt, assigned,
                                        out_labels, out_bbox4, (float4*)out_scores);
    dim3 pg((A_N + 255) / 256, NCHUNK);
    k_pairs<<<pg, 256, 0, stream>>>(pred_scores, pred_bboxes, anchor_points,
                                    gt_labels, gt_bboxes, logsum, bucket, cnt);
    k_select<<<G_N, 64, 0, stream>>>(bucket, cnt, pred_bboxes, gt_bboxes,
                                     assigned, poslist);
    k_fix<<<(G_N * KK + 255) / 256, 256, 0, stream>>>(poslist, assigned, gt_labels,
                                                      gt_bboxes, pred_bboxes,
                                                      out_labels, out_bbox4, out_scores);
}

// Round 11
// 43.915 us; speedup vs baseline: 2.5161x; 1.0427x over previous
//
#include <hip/hip_runtime.h>
#include <climits>

#define A_N 33600
#define G_N 256
#define NC 80
#define KK 10
#define GCHUNK 32
#define NCHUNK (G_N / GCHUNK)    // 8
#define AB_N 132                 // ceil(A_N/256)
#define PAIR_BLKS (AB_N * NCHUNK)          // 1056
#define INIT_BLKS (A_N / 4)                // 8400 (one wave per anchor for logsum)
#define NW (AB_N * 4)            // 528 mask words per gt (word w covers anchors w*64..)
#define FILL_N ((A_N * 81) / 4)  // 680400 float4 of out_scores

// Monotone float->uint mapping: preserves total order (incl. +/-inf).
__device__ __forceinline__ unsigned int ford(float f) {
    unsigned int u = __float_as_uint(f);
    return (u & 0x80000000u) ? ~u : (u | 0x80000000u);
}

__device__ __forceinline__ unsigned long long umin64(unsigned long long a, unsigned long long b) {
    return a < b ? a : b;
}

// Phase 1, two independent roles in one dispatch (no cross-role dependency):
//  bid < PAIR_BLKS: geometric pair sweep. Per (wave, gt): one ballot of
//    (inside && overlap>0) stored to its OWN mask word — every word written
//    unconditionally, so no zero-init, no atomics, no cnt array.
//    inside == in_gt exactly (RADIUS=2.5 makes the center test redundant).
//  bid >= PAIR_BLKS: logsum once per anchor (one wave each) + assigned=-1 +
//    negative-default outputs (labels=80, bbox=0, scores=0).
__global__ __launch_bounds__(256) void k_phase1(
    const float* __restrict__ scores, const float* __restrict__ pred_b,
    const float* __restrict__ anchors, const float* __restrict__ gt_b,
    unsigned long long* __restrict__ mask, float* __restrict__ logsum,
    int* __restrict__ assigned,
    float* __restrict__ out_labels, float4* __restrict__ out_bbox4,
    float4* __restrict__ out_scores4)
{
    int bid = blockIdx.x, tid = threadIdx.x;
    int lane = tid & 63, wid = tid >> 6;

    if (bid < PAIR_BLKS) {         // ---- pair sweep role ----
        __shared__ float4 gbox[GCHUNK];
        int gc = bid & (NCHUNK - 1);
        int ab = bid >> 3;
        if (tid < GCHUNK) gbox[tid] = ((const float4*)gt_b)[gc * GCHUNK + tid];
        __syncthreads();

        int a = ab * 256 + tid;
        bool valid = a < A_N;
        int as = valid ? a : (A_N - 1);
        float4 pb = ((const float4*)pred_b)[as];
        float2 ap = ((const float2*)anchors)[as];
        int word = ab * 4 + wid;   // anchors word*64 .. word*64+63

        #pragma unroll 4
        for (int g = 0; g < GCHUNK; g++) {
            float4 gb = gbox[g];   // LDS broadcast
            bool in_gt = valid &&
                (ap.x >= gb.x) && (ap.x <= gb.z) && (ap.y >= gb.y) && (ap.y <= gb.w);
            unsigned long long em = 0;
            if (__ballot(in_gt)) {
                float ltx = fmaxf(gb.x, pb.x), lty = fmaxf(gb.y, pb.y);
                float rbx = fminf(gb.z, pb.z), rby = fminf(gb.w, pb.w);
                float w = fmaxf(rbx - ltx, 0.f), h = fmaxf(rby - lty, 0.f);
                em = __ballot(in_gt && (w * h > 0.f));
            }
            if (lane == 0) mask[(size_t)(gc * GCHUNK + g) * NW + word] = em;
        }
        return;
    }

    // ---- init role ----
    int t = (bid - PAIR_BLKS) * 256 + tid;
    float4 z4 = make_float4(0.f, 0.f, 0.f, 0.f);
    if (t < A_N) { assigned[t] = -1; out_labels[t] = (float)NC; out_bbox4[t] = z4; }
    if (t < FILL_N) out_scores4[t] = z4;

    // logsum[a] = sum_c log_sigmoid(-s[a,c]) = -sum_c (max(s,0)+log1p(exp(-|s|)))
    int wv = t >> 6;
    const float* row = scores + (long)wv * NC;
    float acc = 0.f;
    for (int c = lane; c < NC; c += 64) {
        float s = row[c];
        acc -= (fmaxf(s, 0.f) + log1pf(expf(-fabsf(s))));
    }
    #pragma unroll
    for (int off = 32; off > 0; off >>= 1) acc += __shfl_down(acc, off);
    if (lane == 0) logsum[wv] = acc;
}

// One WAVE per gt: popcount the mask (exact cnt), compute cost for each set bit
// (bit-identical expression to prior validated rounds), per-lane sorted top-10,
// wave merge-pop for the global k smallest, scatter atomicMax, record poslist.
// cnt==0: lazy early-break ascending scan (lowest-index anchor with overlap>0:
// iou>0 anchors tie at cost exactly 1e10 -> index tiebreak; iou==0 is +inf).
__global__ __launch_bounds__(64) void k_select(
    const unsigned long long* __restrict__ mask, const float* __restrict__ scores,
    const float* __restrict__ logsum, const float* __restrict__ pred_b,
    const float* __restrict__ gt_b, const int* __restrict__ gt_labels,
    int* __restrict__ assigned, int* __restrict__ poslist)
{
    int g = blockIdx.x, lane = threadIdx.x;
    const unsigned long long* mr = mask + (size_t)g * NW;

    unsigned long long wbuf[9];    // 528 = 8*64 + 16
    int cnt = 0;
    #pragma unroll
    for (int i = 0; i < 9; i++) {
        int idx = i * 64 + lane;
        wbuf[i] = (idx < NW) ? mr[idx] : 0ull;
        cnt += __popcll(wbuf[i]);
    }
    #pragma unroll
    for (int off = 32; off; off >>= 1) cnt += __shfl_xor(cnt, off);

    float4 gb = ((const float4*)gt_b)[g];

    if (cnt == 0) {
        int found = INT_MAX;
        for (int base = 0; base < A_N; base += 64) {     // A_N = 525*64 exact
            int a = base + lane;
            float4 pbx = ((const float4*)pred_b)[a];
            float w = fminf(gb.z, pbx.z) - fmaxf(gb.x, pbx.x);
            float h = fminf(gb.w, pbx.w) - fmaxf(gb.y, pbx.y);
            bool hit = (w > 0.f) && (h > 0.f);
            if (__ballot(hit)) { if (hit) found = a; break; }  // first hit batch holds the min
        }
        #pragma unroll
        for (int off = 32; off; off >>= 1) found = min(found, __shfl_xor(found, off));
        int m = (found == INT_MAX) ? 0 : found;
        if (lane == 0) atomicMax(&assigned[m], g);
        if (lane < KK) poslist[g * KK + lane] = (lane == 0) ? m : -1;
        return;
    }

    int lg = gt_labels[g];
    float area_g = (gb.z - gb.x) * (gb.w - gb.y);

    unsigned long long p[KK];
    #pragma unroll
    for (int i = 0; i < KK; i++) p[i] = ~0ull;

    #pragma unroll
    for (int i = 0; i < 9; i++) {
        unsigned long long bits = wbuf[i];
        int abase = (i * 64 + lane) * 64;
        while (bits) {
            int b = __builtin_ctzll(bits);
            bits &= bits - 1;
            int a = abase + b;
            float4 pbx = ((const float4*)pred_b)[a];
            float ltx = fmaxf(gb.x, pbx.x), lty = fmaxf(gb.y, pbx.y);
            float rbx = fminf(gb.z, pbx.z), rby = fminf(gb.w, pbx.w);
            float w = fmaxf(rbx - ltx, 0.f), h = fmaxf(rby - lty, 0.f);
            float overlap = w * h;
            float area_p = (pbx.z - pbx.x) * (pbx.w - pbx.y);
            float uni = area_g + area_p - overlap + 1e-6f;
            float iou = overlap / uni;
            float s = scores[(long)a * NC + lg];
            // log_sigmoid(s)-log_sigmoid(-s) == s (shared log1p term cancels)
            float cost = (-s - logsum[a]) + 3.0f * (-logf(iou));
            unsigned long long key = ((unsigned long long)ford(cost) << 32) | (unsigned)a;
            if (key < p[KK - 1]) {
                p[KK - 1] = key;           // insert + bubble (static indices)
                #pragma unroll
                for (int k2 = KK - 1; k2 > 0; k2--) {
                    unsigned long long lo = p[k2-1] < p[k2] ? p[k2-1] : p[k2];
                    unsigned long long hi = p[k2-1] < p[k2] ? p[k2]   : p[k2-1];
                    p[k2-1] = lo; p[k2] = hi;
                }
            }
        }
    }

    int k = cnt < KK ? cnt : KK;
    int mywin = -1;
    for (int it = 0; it < k; it++) {
        unsigned long long m = p[0];
        #pragma unroll
        for (int off = 32; off; off >>= 1) m = umin64(m, __shfl_xor(m, off));
        if (lane == it) mywin = (int)(m & 0xffffffffu);
        bool win = (p[0] == m);    // keys unique -> exactly one lane
        if (win) {                 // pop head (static shift)
            #pragma unroll
            for (int k2 = 0; k2 < KK - 1; k2++) p[k2] = p[k2 + 1];
            p[KK - 1] = ~0ull;
        }
    }

    if (lane < KK) poslist[g * KK + lane] = (lane < k) ? mywin : -1;
    if (lane < k) atomicMax(&assigned[mywin], g);
}

// Positives-only output fix-up: <=2560 candidate anchors; assigned[] is final
// (stream order). Duplicate entries write identical values -> deterministic.
__global__ __launch_bounds__(256) void k_fix(
    const int* __restrict__ poslist, const int* __restrict__ assigned,
    const int* __restrict__ gt_labels, const float* __restrict__ gt_b,
    const float* __restrict__ pred_b,
    float* __restrict__ out_labels, float4* __restrict__ out_bbox4,
    float* __restrict__ out_scores)
{
    int t = blockIdx.x * 256 + threadIdx.x;
    if (t >= G_N * KK) return;
    int a = poslist[t];
    if (a < 0) return;
    int g = assigned[a];               // final; >= 0 since a was scattered by someone
    int label = gt_labels[g];
    float4 gb = ((const float4*)gt_b)[g];
    float4 pb = ((const float4*)pred_b)[a];
    float w = fminf(gb.z, pb.z) - fmaxf(gb.x, pb.x);
    float h = fminf(gb.w, pb.w) - fmaxf(gb.y, pb.y);
    float ovl = fmaxf(w, 0.f) * fmaxf(h, 0.f);
    float area_g = (gb.z - gb.x) * (gb.w - gb.y);
    float area_p = (pb.z - pb.x) * (pb.w - pb.y);
    float uni = area_g + area_p - ovl + 1e-6f;
    float iou = ovl / uni;
    out_labels[a] = (float)label;
    out_bbox4[a] = gb;
    out_scores[(long)a * (NC + 1) + label] = iou;
}

extern "C" void kernel_launch(void* const* d_in, const int* in_sizes, int n_in,
                              void* d_out, int out_size, void* d_ws, size_t ws_size,
                              hipStream_t stream) {
    const float* pred_scores   = (const float*)d_in[0];
    const float* pred_bboxes   = (const float*)d_in[1];
    const float* anchor_points = (const float*)d_in[2];
    const int*   gt_labels     = (const int*)d_in[3];
    const float* gt_bboxes     = (const float*)d_in[4];

    char* ws = (char*)d_ws;
    unsigned long long* mask = (unsigned long long*)ws;      // G*NW u64 = 1.08 MB (8B-aligned first)
    size_t off = (size_t)G_N * NW * 8;
    int*   assigned = (int*)(ws + off);   off += (size_t)A_N * 4;
    int*   poslist  = (int*)(ws + off);   off += (size_t)G_N * KK * 4;
    float* logsum   = (float*)(ws + off);

    float*  out_labels = (float*)d_out;                 // A
    float4* out_bbox4  = (float4*)(out_labels + A_N);   // A float4 (16B-aligned)
    float*  out_scores = out_labels + 5 * (size_t)A_N;  // A*81 (16B-aligned)

    k_phase1<<<PAIR_BLKS + INIT_BLKS, 256, 0, stream>>>(
        pred_scores, pred_bboxes, anchor_points, gt_bboxes,
        mask, logsum, assigned, out_labels, out_bbox4, (float4*)out_scores);
    k_select<<<G_N, 64, 0, stream>>>(mask, pred_scores, logsum, pred_bboxes,
                                     gt_bboxes, gt_labels, assigned, poslist);
    k_fix<<<(G_N * KK + 255) / 256, 256, 0, stream>>>(poslist, assigned, gt_labels,
                                                      gt_bboxes, pred_bboxes,
                                                      out_labels, out_bbox4, out_scores);
}